// Round 10
// baseline (30.585 us; speedup 1.0000x reference)
//
#include <hip/hip_runtime.h>
#include <hip/hip_bf16.h>

typedef __attribute__((ext_vector_type(8))) short bf16x8;
typedef __attribute__((ext_vector_type(4))) float f32x4;

__device__ __forceinline__ unsigned short f2bf(float f) {
    unsigned u = __builtin_bit_cast(unsigned, f);
    unsigned rnd = 0x7FFFu + ((u >> 16) & 1u);
    return (unsigned short)((u + rnd) >> 16);
}

// ---------------------------------------------------------------------------
// Setup: simulate the circuit on the 256 basis vectors -> U (256x256),
// packed as bf16 fragments (same map for A- or B-operand; R8-verified):
//   element (n,k): u=n>>4, t=k>>5, lane=((k>>3)&3)*16+(n&15), j=k&7
//   Bp[((u*8+t)*64 + lane)*8 + j]
// ---------------------------------------------------------------------------
__global__ __launch_bounds__(256) void qnn_setup(const float* __restrict__ wts,
                                                 unsigned short* __restrict__ Bp) {
    __shared__ float cs[56], sn[56];
    int tid = threadIdx.x;
    if (tid < 56) {
        float th = 0.5f * wts[tid];
        cs[tid] = cosf(th);
        sn[tid] = sinf(th);
    }
    __syncthreads();

    int l = tid & 63;
    int k = blockIdx.x * 4 + (tid >> 6);   // column 0..255
    int a0 = l << 2;

    float v0 = (float)(a0 + 0 == k);
    float v1 = (float)(a0 + 1 == k);
    float v2 = (float)(a0 + 2 == k);
    float v3 = (float)(a0 + 3 == k);

#pragma unroll
    for (int L = 0; L < 7; ++L) {
#pragma unroll
        for (int q = 0; q <= 5; ++q) {     // RY wires 0..5 (lane bits)
            int m = 5 - q;
            float c = cs[L * 8 + q], s = sn[L * 8 + q];
            float ss = ((l >> m) & 1) ? s : -s;
            float p0 = __shfl_xor(v0, 1 << m);
            float p1 = __shfl_xor(v1, 1 << m);
            float p2 = __shfl_xor(v2, 1 << m);
            float p3 = __shfl_xor(v3, 1 << m);
            v0 = fmaf(ss, p0, c * v0);
            v1 = fmaf(ss, p1, c * v1);
            v2 = fmaf(ss, p2, c * v2);
            v3 = fmaf(ss, p3, c * v3);
        }
        {   // RY wire 6 (reg bit 1)
            float c = cs[L * 8 + 6], s = sn[L * 8 + 6];
            float n0 = fmaf(-s, v2, c * v0), n2 = fmaf(s, v0, c * v2);
            float n1 = fmaf(-s, v3, c * v1), n3 = fmaf(s, v1, c * v3);
            v0 = n0; v1 = n1; v2 = n2; v3 = n3;
        }
        {   // RY wire 7 (reg bit 0)
            float c = cs[L * 8 + 7], s = sn[L * 8 + 7];
            float n0 = fmaf(-s, v1, c * v0), n1 = fmaf(s, v0, c * v1);
            float n2 = fmaf(-s, v3, c * v2), n3 = fmaf(s, v2, c * v3);
            v0 = n0; v1 = n1; v2 = n2; v3 = n3;
        }
        {   // CNOTs q=0..4 (both bits in lane index): composed lane permute
            int src = l;
#pragma unroll
            for (int q = 4; q >= 0; --q)
                src = src ^ (((src >> (5 - q)) & 1) << (4 - q));
            v0 = __shfl(v0, src);
            v1 = __shfl(v1, src);
            v2 = __shfl(v2, src);
            v3 = __shfl(v3, src);
        }
        {   // CNOT q=5: ctl = lane bit0, tgt = reg bit1
            bool cc = (l & 1);
            float n0 = cc ? v2 : v0, n2 = cc ? v0 : v2;
            float n1 = cc ? v3 : v1, n3 = cc ? v1 : v3;
            v0 = n0; v1 = n1; v2 = n2; v3 = n3;
        }
        {   // CNOT q=6: swap v2,v3
            float t = v2; v2 = v3; v3 = t;
        }
    }

    int t = k >> 5, j = k & 7, lk = (k >> 3) & 3;
#pragma unroll
    for (int r = 0; r < 4; ++r) {
        int n = a0 + r;
        int u = n >> 4;
        int ls = lk * 16 + (n & 15);
        float val = (r == 0) ? v0 : (r == 1) ? v1 : (r == 2) ? v2 : v3;
        Bp[(((u * 8 + t) * 64) + ls) * 8 + j] = f2bf(val);
    }
}

#define ROWF 260   // floats per padded LDS row (1040 B = 65*16: 2-way-free banks)

// wave w DMA-stages rows 8w..8w+7 of a 32-sample fp32 tile (1 KB/row/instr)
__device__ __forceinline__ void stage_tile(const float* __restrict__ xg,
                                           float* dstbase, int w, int l) {
#pragma unroll
    for (int i = 0; i < 8; ++i) {
        int r = w * 8 + i;
        __builtin_amdgcn_global_load_lds(
            (const __attribute__((address_space(1))) void*)
                ((const char*)xg + (size_t)r * 1024 + l * 16),
            (__attribute__((address_space(3))) void*)
                ((char*)dstbase + r * 1040),
            16, 0, 0);
    }
}

// ---------------------------------------------------------------------------
// Main (R10): 512 blocks x 256 thr (4 waves), 128 samples/block, 2 blocks/CU.
// x staged fp32 via global_load_lds DMA (no VGPR burst to serialize) into
// double-buffered padded LDS tiles; counted vmcnt (T4) keeps next tile's DMA
// in flight through compute. U register-resident: wave w holds u-blocks
// 4w..4w+3 (128 VGPR). Each x ds_read feeds 4 MFMAs. Sign via wave pairs.
// ---------------------------------------------------------------------------
__global__ __launch_bounds__(256, 2) void qnn_main(
    const float* __restrict__ x, const unsigned short* __restrict__ Bp,
    const float* __restrict__ W1, const float* __restrict__ b1,
    const float* __restrict__ W2, const float* __restrict__ b2,
    float* __restrict__ out) {
    __shared__ __align__(16) float XsF[2][32 * ROWF];      // 2 x 33280 B
    __shared__ float Qpart[4][128];
    __shared__ float Nrm[128];

    int tid = threadIdx.x;
    int l = tid & 63, w = tid >> 6;                        // wave 0..3
    size_t base = (size_t)blockIdx.x * 128 * 256;          // 128 samples/block
    const float* xb = x + base;

    // ---- U fragments: wave w -> u-blocks 4w..4w+3 (issued first) ----
    const unsigned short* up = Bp + (size_t)(4 * w) * 4096 + l * 8;
    bf16x8 uf0[8], uf1[8], uf2[8], uf3[8];
#pragma unroll
    for (int t = 0; t < 8; ++t) {
        uf0[t] = *(const bf16x8*)(up + t * 512);
        uf1[t] = *(const bf16x8*)(up + 4096 + t * 512);
        uf2[t] = *(const bf16x8*)(up + 8192 + t * 512);
        uf3[t] = *(const bf16x8*)(up + 12288 + t * 512);
    }
    __builtin_amdgcn_sched_barrier(0);
    stage_tile(xb, XsF[0], w, l);                          // tile 0 -> buf0
    __builtin_amdgcn_sched_barrier(0);
    stage_tile(xb + 32 * 256, XsF[1], w, l);               // tile 1 -> buf1
    __builtin_amdgcn_sched_barrier(0);
    asm volatile("s_waitcnt vmcnt(8)" ::: "memory");       // uf + tile0 done
    __builtin_amdgcn_sched_barrier(0);
    __builtin_amdgcn_s_barrier();

    int sl = l & 15, kg = l >> 4;

#pragma unroll
    for (int t = 0; t < 4; ++t) {
        const float* buf = XsF[t & 1];
        // ---- compute tile t: 2 tau x (8 ksteps x [2 ds_read -> 4 MFMA]) ----
#pragma unroll
        for (int tau = 0; tau < 2; ++tau) {
            const float* row = buf + (tau * 16 + sl) * ROWF + kg * 8;
            f32x4 a0 = {0.f, 0.f, 0.f, 0.f}, a1 = {0.f, 0.f, 0.f, 0.f};
            f32x4 a2 = {0.f, 0.f, 0.f, 0.f}, a3 = {0.f, 0.f, 0.f, 0.f};
            float ss = 0.f;
#pragma unroll
            for (int ks = 0; ks < 8; ++ks) {
                float4 f0 = *(const float4*)(row + ks * 32);
                float4 f1 = *(const float4*)(row + ks * 32 + 4);
                ss = fmaf(f0.x, f0.x, fmaf(f0.y, f0.y, fmaf(f0.z, f0.z, fmaf(f0.w, f0.w, ss))));
                ss = fmaf(f1.x, f1.x, fmaf(f1.y, f1.y, fmaf(f1.z, f1.z, fmaf(f1.w, f1.w, ss))));
                bf16x8 xf;
                xf[0] = (short)f2bf(f0.x); xf[1] = (short)f2bf(f0.y);
                xf[2] = (short)f2bf(f0.z); xf[3] = (short)f2bf(f0.w);
                xf[4] = (short)f2bf(f1.x); xf[5] = (short)f2bf(f1.y);
                xf[6] = (short)f2bf(f1.z); xf[7] = (short)f2bf(f1.w);
                a0 = __builtin_amdgcn_mfma_f32_16x16x32_bf16(uf0[ks], xf, a0, 0, 0, 0);
                a1 = __builtin_amdgcn_mfma_f32_16x16x32_bf16(uf1[ks], xf, a1, 0, 0, 0);
                a2 = __builtin_amdgcn_mfma_f32_16x16x32_bf16(uf2[ks], xf, a2, 0, 0, 0);
                a3 = __builtin_amdgcn_mfma_f32_16x16x32_bf16(uf3[ks], xf, a3, 0, 0, 0);
            }
            // norms (fp32, redundant across waves; wave 0 publishes)
            ss += __shfl_xor(ss, 16);
            ss += __shfl_xor(ss, 32);
            // q = sum over this wave's 64 n-rows of w^2
            float q = 0.f;
#pragma unroll
            for (int j = 0; j < 4; ++j) {
                q = fmaf(a0[j], a0[j], q);
                q = fmaf(a1[j], a1[j], q);
                q = fmaf(a2[j], a2[j], q);
                q = fmaf(a3[j], a3[j], q);
            }
            q += __shfl_xor(q, 16);
            q += __shfl_xor(q, 32);
            if (l < 16) {
                Qpart[w][t * 32 + tau * 16 + l] = q;
                if (w == 0) Nrm[t * 32 + tau * 16 + l] = ss;
            }
        }
        // ---- pipeline control ----
        __builtin_amdgcn_s_barrier();                      // all done reading buf
        if (t < 2) {
            stage_tile(xb + (size_t)(t + 2) * 32 * 256, XsF[t & 1], w, l);
            __builtin_amdgcn_sched_barrier(0);
        }
        if (t < 3) {
            if (t < 2) asm volatile("s_waitcnt vmcnt(8)" ::: "memory");
            else       asm volatile("s_waitcnt vmcnt(0)" ::: "memory");
            __builtin_amdgcn_sched_barrier(0);
            __builtin_amdgcn_s_barrier();                  // next buf staged everywhere
        }
    }

    // ---- epilogue: signed combine, norm, MLP, sigmoid ----
    __syncthreads();
    if (tid < 128) {
        float p = Qpart[0][tid] + Qpart[1][tid] - Qpart[2][tid] - Qpart[3][tid];
        float z = p / Nrm[tid];
        float o = b2[0];
#pragma unroll
        for (int jj = 0; jj < 16; ++jj) {
            float h = fmaf(z, W1[jj], b1[jj]);
            h = h > 0.f ? h : 0.f;
            o = fmaf(W2[jj], h, o);
        }
        out[(size_t)blockIdx.x * 128 + tid] = 1.f / (1.f + expf(-o));
    }
}

extern "C" void kernel_launch(void* const* d_in, const int* in_sizes, int n_in,
                              void* d_out, int out_size, void* d_ws, size_t ws_size,
                              hipStream_t stream) {
    const float* x   = (const float*)d_in[0];
    const float* wts = (const float*)d_in[1];
    const float* W1  = (const float*)d_in[2];
    const float* b1  = (const float*)d_in[3];
    const float* W2  = (const float*)d_in[4];
    const float* b2  = (const float*)d_in[5];
    float* out = (float*)d_out;
    unsigned short* Bp = (unsigned short*)d_ws;   // 65536 bf16 = 128 KB

    int B = in_sizes[0] >> 8;        // 65536 samples
    qnn_setup<<<64, 256, 0, stream>>>(wts, Bp);
    qnn_main<<<B / 128, 256, 0, stream>>>(x, Bp, W1, b1, W2, b2, out);
}

// Round 12
// 23.910 us; speedup vs baseline: 1.2792x; 1.2792x over previous
//
#include <hip/hip_runtime.h>
#include <hip/hip_bf16.h>

typedef __attribute__((ext_vector_type(8))) short bf16x8;
typedef __attribute__((ext_vector_type(4))) float f32x4;

__device__ __forceinline__ unsigned short f2bf(float f) {
    unsigned u = __builtin_bit_cast(unsigned, f);
    unsigned rnd = 0x7FFFu + ((u >> 16) & 1u);
    return (unsigned short)((u + rnd) >> 16);
}

// raw barrier: lgkmcnt drain (LDS writes visible) WITHOUT vmcnt drain, so
// in-flight global prefetch loads survive the barrier (R9-verified).
__device__ __forceinline__ void wg_barrier() {
    asm volatile("s_waitcnt lgkmcnt(0)" ::: "memory");
    __builtin_amdgcn_sched_barrier(0);
    __builtin_amdgcn_s_barrier();
    __builtin_amdgcn_sched_barrier(0);
}

// ---------------------------------------------------------------------------
// Setup: simulate the circuit on the 256 basis vectors -> U (256x256),
// packed as bf16 fragments (same map for A- or B-operand; R8-verified):
//   element (n,k): u=n>>4, t=k>>5, lane=((k>>3)&3)*16+(n&15), j=k&7
//   Bp[((u*8+t)*64 + lane)*8 + j]
// ---------------------------------------------------------------------------
__global__ __launch_bounds__(256) void qnn_setup(const float* __restrict__ wts,
                                                 unsigned short* __restrict__ Bp) {
    __shared__ float cs[56], sn[56];
    int tid = threadIdx.x;
    if (tid < 56) {
        float th = 0.5f * wts[tid];
        cs[tid] = cosf(th);
        sn[tid] = sinf(th);
    }
    __syncthreads();

    int l = tid & 63;
    int k = blockIdx.x * 4 + (tid >> 6);   // column 0..255
    int a0 = l << 2;

    float v0 = (float)(a0 + 0 == k);
    float v1 = (float)(a0 + 1 == k);
    float v2 = (float)(a0 + 2 == k);
    float v3 = (float)(a0 + 3 == k);

#pragma unroll
    for (int L = 0; L < 7; ++L) {
#pragma unroll
        for (int q = 0; q <= 5; ++q) {     // RY wires 0..5 (lane bits)
            int m = 5 - q;
            float c = cs[L * 8 + q], s = sn[L * 8 + q];
            float ss = ((l >> m) & 1) ? s : -s;
            float p0 = __shfl_xor(v0, 1 << m);
            float p1 = __shfl_xor(v1, 1 << m);
            float p2 = __shfl_xor(v2, 1 << m);
            float p3 = __shfl_xor(v3, 1 << m);
            v0 = fmaf(ss, p0, c * v0);
            v1 = fmaf(ss, p1, c * v1);
            v2 = fmaf(ss, p2, c * v2);
            v3 = fmaf(ss, p3, c * v3);
        }
        {   // RY wire 6 (reg bit 1)
            float c = cs[L * 8 + 6], s = sn[L * 8 + 6];
            float n0 = fmaf(-s, v2, c * v0), n2 = fmaf(s, v0, c * v2);
            float n1 = fmaf(-s, v3, c * v1), n3 = fmaf(s, v1, c * v3);
            v0 = n0; v1 = n1; v2 = n2; v3 = n3;
        }
        {   // RY wire 7 (reg bit 0)
            float c = cs[L * 8 + 7], s = sn[L * 8 + 7];
            float n0 = fmaf(-s, v1, c * v0), n1 = fmaf(s, v0, c * v1);
            float n2 = fmaf(-s, v3, c * v2), n3 = fmaf(s, v2, c * v3);
            v0 = n0; v1 = n1; v2 = n2; v3 = n3;
        }
        {   // CNOTs q=0..4 (both bits in lane index): composed lane permute
            int src = l;
#pragma unroll
            for (int q = 4; q >= 0; --q)
                src = src ^ (((src >> (5 - q)) & 1) << (4 - q));
            v0 = __shfl(v0, src);
            v1 = __shfl(v1, src);
            v2 = __shfl(v2, src);
            v3 = __shfl(v3, src);
        }
        {   // CNOT q=5: ctl = lane bit0, tgt = reg bit1
            bool cc = (l & 1);
            float n0 = cc ? v2 : v0, n2 = cc ? v0 : v2;
            float n1 = cc ? v3 : v1, n3 = cc ? v1 : v3;
            v0 = n0; v1 = n1; v2 = n2; v3 = n3;
        }
        {   // CNOT q=6: swap v2,v3
            float t = v2; v2 = v3; v3 = t;
        }
    }

    int t = k >> 5, j = k & 7, lk = (k >> 3) & 3;
#pragma unroll
    for (int r = 0; r < 4; ++r) {
        int n = a0 + r;
        int u = n >> 4;
        int ls = lk * 16 + (n & 15);
        float val = (r == 0) ? v0 : (r == 1) ? v1 : (r == 2) ? v2 : v3;
        Bp[(((u * 8 + t) * 64) + ls) * 8 + j] = f2bf(val);
    }
}

// convert one thread's 8 floats of a 16-row tile, store swizzled, norms
__device__ __forceinline__ void cvt_store(const float4& a, const float4& b,
                                          unsigned short (*Xp)[256],
                                          float* NrmT, int sr, int qt) {
    float ss = fmaf(a.x, a.x, fmaf(a.y, a.y, fmaf(a.z, a.z, a.w * a.w)));
    ss = fmaf(b.x, b.x, fmaf(b.y, b.y, fmaf(b.z, b.z, fmaf(b.w, b.w, ss))));
    bf16x8 h;
    h[0] = (short)f2bf(a.x); h[1] = (short)f2bf(a.y);
    h[2] = (short)f2bf(a.z); h[3] = (short)f2bf(a.w);
    h[4] = (short)f2bf(b.x); h[5] = (short)f2bf(b.y);
    h[6] = (short)f2bf(b.z); h[7] = (short)f2bf(b.w);
    *(bf16x8*)&Xp[sr][(qt ^ (sr & 7)) * 8] = h;       // bijective XOR swizzle
    // row norm: 32 lanes per row (half-wave), xor-reduce
    ss += __shfl_xor(ss, 1);
    ss += __shfl_xor(ss, 2);
    ss += __shfl_xor(ss, 4);
    ss += __shfl_xor(ss, 8);
    ss += __shfl_xor(ss, 16);
    if (qt == 0) NrmT[sr] = ss;                       // fp32 norm (pre-bf16)
}

// ---------------------------------------------------------------------------
// Main (R12): R9's verified pipeline, but 512 blocks x 512 thr x 128 samples
// with __launch_bounds__(512,4) -> 2 RESIDENT blocks/CU whose phases
// interleave (stage/HBM of one overlaps MFMA/LDS of the other). 16-sample
// tiles, depth-2 prefetch, lgkm-only barriers (vmcnt never drained by
// barriers). U register/AGPR-resident per wave: u-blocks {2w, 2w+1}.
// ---------------------------------------------------------------------------
__global__ __launch_bounds__(512, 4) void qnn_main(
    const float* __restrict__ x, const unsigned short* __restrict__ Bp,
    const float* __restrict__ W1, const float* __restrict__ b1,
    const float* __restrict__ W2, const float* __restrict__ b2,
    float* __restrict__ out) {
    __shared__ __align__(16) unsigned short Xs[2][16][256];   // 16 KB
    __shared__ float Qpart[8][128];                           // 4 KB
    __shared__ float Nrm[128];                                // 512 B

    int tid = threadIdx.x;
    int l = tid & 63, w = tid >> 6;        // wave 0..7
    int sr = tid >> 5, qt = tid & 31;      // staging: row 0..15, 8-float chunk
    size_t base = (size_t)blockIdx.x * 128 * 256;
    const float* xst = x + base + (size_t)sr * 256 + qt * 8;

    // ---- U fragments (u-blocks 2w, 2w+1), loaded once ----
    const unsigned short* up = Bp + (size_t)(2 * w) * 4096 + l * 8;
    bf16x8 uf0[8], uf1[8];
#pragma unroll
    for (int t = 0; t < 8; ++t) {
        uf0[t] = *(const bf16x8*)(up + t * 512);
        uf1[t] = *(const bf16x8*)(up + 4096 + t * 512);
    }

    // ---- prologue: tiles 0,1 prefetched; tile 0 converted to LDS ----
    float4 pf[2][2];
    pf[0][0] = *(const float4*)(xst);
    pf[0][1] = *(const float4*)(xst + 4);
    pf[1][0] = *(const float4*)(xst + 4096);
    pf[1][1] = *(const float4*)(xst + 4100);
    cvt_store(pf[0][0], pf[0][1], Xs[0], Nrm, sr, qt);
    wg_barrier();

    int row = l & 15, kg = l >> 4;

    // ---- 8-tile pipeline: prefetch(t+2) -> compute(t) -> cvt_store(t+1) ----
#pragma unroll
    for (int t = 0; t < 8; ++t) {
        if (t + 2 < 8) {
            pf[t & 1][0] = *(const float4*)(xst + (size_t)(t + 2) * 4096);
            pf[t & 1][1] = *(const float4*)(xst + (size_t)(t + 2) * 4096 + 4);
        }
        {   // compute tile t: 8 ksteps x 2 builtin MFMAs (hazards handled)
            const unsigned short* rp = &Xs[t & 1][row][0];
            f32x4 a0 = {0.f, 0.f, 0.f, 0.f}, a1 = {0.f, 0.f, 0.f, 0.f};
#pragma unroll
            for (int ks = 0; ks < 8; ++ks) {
                bf16x8 xf = *(const bf16x8*)(rp + (((ks << 2) | kg) ^ (row & 7)) * 8);
                a0 = __builtin_amdgcn_mfma_f32_16x16x32_bf16(uf0[ks], xf, a0, 0, 0, 0);
                a1 = __builtin_amdgcn_mfma_f32_16x16x32_bf16(uf1[ks], xf, a1, 0, 0, 0);
            }
            float q = 0.f;
#pragma unroll
            for (int j = 0; j < 4; ++j)
                q = fmaf(a0[j], a0[j], fmaf(a1[j], a1[j], q));
            q += __shfl_xor(q, 16);        // reduce the 4 n-row groups
            q += __shfl_xor(q, 32);
            if (l < 16) Qpart[w][t * 16 + l] = q;
        }
        if (t + 1 < 8)
            cvt_store(pf[(t + 1) & 1][0], pf[(t + 1) & 1][1],
                      Xs[(t + 1) & 1], Nrm + (t + 1) * 16, sr, qt);
        wg_barrier();
    }

    // ---- epilogue: signed combine, norm, MLP, sigmoid ----
    if (tid < 128) {
        float p = Qpart[0][tid] + Qpart[1][tid] + Qpart[2][tid] + Qpart[3][tid]
                - Qpart[4][tid] - Qpart[5][tid] - Qpart[6][tid] - Qpart[7][tid];
        float z = p / Nrm[tid];
        float o = b2[0];
#pragma unroll
        for (int jj = 0; jj < 16; ++jj) {
            float h = fmaf(z, W1[jj], b1[jj]);
            h = h > 0.f ? h : 0.f;
            o = fmaf(W2[jj], h, o);
        }
        out[(size_t)blockIdx.x * 128 + tid] = 1.f / (1.f + expf(-o));
    }
}

extern "C" void kernel_launch(void* const* d_in, const int* in_sizes, int n_in,
                              void* d_out, int out_size, void* d_ws, size_t ws_size,
                              hipStream_t stream) {
    const float* x   = (const float*)d_in[0];
    const float* wts = (const float*)d_in[1];
    const float* W1  = (const float*)d_in[2];
    const float* b1  = (const float*)d_in[3];
    const float* W2  = (const float*)d_in[4];
    const float* b2  = (const float*)d_in[5];
    float* out = (float*)d_out;
    unsigned short* Bp = (unsigned short*)d_ws;   // 65536 bf16 = 128 KB

    int B = in_sizes[0] >> 8;        // 65536 samples
    qnn_setup<<<64, 256, 0, stream>>>(wts, Bp);
    qnn_main<<<B / 128, 512, 0, stream>>>(x, Bp, W1, b1, W2, b2, out);
}

// Round 13
// 22.937 us; speedup vs baseline: 1.3334x; 1.0424x over previous
//
#include <hip/hip_runtime.h>
#include <hip/hip_bf16.h>

typedef __attribute__((ext_vector_type(8))) short bf16x8;
typedef __attribute__((ext_vector_type(4))) float f32x4;

__device__ __forceinline__ unsigned short f2bf(float f) {
    unsigned u = __builtin_bit_cast(unsigned, f);
    unsigned rnd = 0x7FFFu + ((u >> 16) & 1u);
    return (unsigned short)((u + rnd) >> 16);
}

// raw barrier: lgkmcnt drain (LDS writes visible) WITHOUT vmcnt drain, so
// in-flight global prefetch loads survive the barrier (R9/R12-verified).
__device__ __forceinline__ void wg_barrier() {
    asm volatile("s_waitcnt lgkmcnt(0)" ::: "memory");
    __builtin_amdgcn_sched_barrier(0);
    __builtin_amdgcn_s_barrier();
    __builtin_amdgcn_sched_barrier(0);
}

// ---------------------------------------------------------------------------
// Setup: simulate the circuit on the 256 basis vectors -> U (256x256),
// packed as bf16 fragments (same map for A- or B-operand; R8-verified):
//   element (n,k): u=n>>4, t=k>>5, lane=((k>>3)&3)*16+(n&15), j=k&7
//   Bp[((u*8+t)*64 + lane)*8 + j]
// ---------------------------------------------------------------------------
__global__ __launch_bounds__(256) void qnn_setup(const float* __restrict__ wts,
                                                 unsigned short* __restrict__ Bp) {
    __shared__ float cs[56], sn[56];
    int tid = threadIdx.x;
    if (tid < 56) {
        float th = 0.5f * wts[tid];
        cs[tid] = cosf(th);
        sn[tid] = sinf(th);
    }
    __syncthreads();

    int l = tid & 63;
    int k = blockIdx.x * 4 + (tid >> 6);   // column 0..255
    int a0 = l << 2;

    float v0 = (float)(a0 + 0 == k);
    float v1 = (float)(a0 + 1 == k);
    float v2 = (float)(a0 + 2 == k);
    float v3 = (float)(a0 + 3 == k);

#pragma unroll
    for (int L = 0; L < 7; ++L) {
#pragma unroll
        for (int q = 0; q <= 5; ++q) {     // RY wires 0..5 (lane bits)
            int m = 5 - q;
            float c = cs[L * 8 + q], s = sn[L * 8 + q];
            float ss = ((l >> m) & 1) ? s : -s;
            float p0 = __shfl_xor(v0, 1 << m);
            float p1 = __shfl_xor(v1, 1 << m);
            float p2 = __shfl_xor(v2, 1 << m);
            float p3 = __shfl_xor(v3, 1 << m);
            v0 = fmaf(ss, p0, c * v0);
            v1 = fmaf(ss, p1, c * v1);
            v2 = fmaf(ss, p2, c * v2);
            v3 = fmaf(ss, p3, c * v3);
        }
        {   // RY wire 6 (reg bit 1)
            float c = cs[L * 8 + 6], s = sn[L * 8 + 6];
            float n0 = fmaf(-s, v2, c * v0), n2 = fmaf(s, v0, c * v2);
            float n1 = fmaf(-s, v3, c * v1), n3 = fmaf(s, v1, c * v3);
            v0 = n0; v1 = n1; v2 = n2; v3 = n3;
        }
        {   // RY wire 7 (reg bit 0)
            float c = cs[L * 8 + 7], s = sn[L * 8 + 7];
            float n0 = fmaf(-s, v1, c * v0), n1 = fmaf(s, v0, c * v1);
            float n2 = fmaf(-s, v3, c * v2), n3 = fmaf(s, v2, c * v3);
            v0 = n0; v1 = n1; v2 = n2; v3 = n3;
        }
        {   // CNOTs q=0..4 (both bits in lane index): composed lane permute
            int src = l;
#pragma unroll
            for (int q = 4; q >= 0; --q)
                src = src ^ (((src >> (5 - q)) & 1) << (4 - q));
            v0 = __shfl(v0, src);
            v1 = __shfl(v1, src);
            v2 = __shfl(v2, src);
            v3 = __shfl(v3, src);
        }
        {   // CNOT q=5: ctl = lane bit0, tgt = reg bit1
            bool cc = (l & 1);
            float n0 = cc ? v2 : v0, n2 = cc ? v0 : v2;
            float n1 = cc ? v3 : v1, n3 = cc ? v1 : v3;
            v0 = n0; v1 = n1; v2 = n2; v3 = n3;
        }
        {   // CNOT q=6: swap v2,v3
            float t = v2; v2 = v3; v3 = t;
        }
    }

    int t = k >> 5, j = k & 7, lk = (k >> 3) & 3;
#pragma unroll
    for (int r = 0; r < 4; ++r) {
        int n = a0 + r;
        int u = n >> 4;
        int ls = lk * 16 + (n & 15);
        float val = (r == 0) ? v0 : (r == 1) ? v1 : (r == 2) ? v2 : v3;
        Bp[(((u * 8 + t) * 64) + ls) * 8 + j] = f2bf(val);
    }
}

// convert one thread's 8 floats of a 16-row tile, store swizzled.
// NO norm computation: U is orthogonal, so ||Ux||^2 = ||x||^2 and the
// denominator comes free from the signed sums (R13).
__device__ __forceinline__ void cvt_store(const float4& a, const float4& b,
                                          unsigned short (*Xp)[256],
                                          int sr, int qt) {
    bf16x8 h;
    h[0] = (short)f2bf(a.x); h[1] = (short)f2bf(a.y);
    h[2] = (short)f2bf(a.z); h[3] = (short)f2bf(a.w);
    h[4] = (short)f2bf(b.x); h[5] = (short)f2bf(b.y);
    h[6] = (short)f2bf(b.z); h[7] = (short)f2bf(b.w);
    *(bf16x8*)&Xp[sr][(qt ^ (sr & 7)) * 8] = h;       // bijective XOR swizzle
}

// ---------------------------------------------------------------------------
// Main (R13): R12's verified 2-blocks/CU pipeline with the norm path deleted
// (orthogonality: z = (P+ - P-)/(P+ + P-)). 512 blocks x 512 thr x 128
// samples; 16-sample tiles, depth-2 prefetch, lgkm-only barriers.
// U resident per wave: u-blocks {2w, 2w+1}; waves 0-3 "+", 4-7 "-".
// ---------------------------------------------------------------------------
__global__ __launch_bounds__(512, 4) void qnn_main(
    const float* __restrict__ x, const unsigned short* __restrict__ Bp,
    const float* __restrict__ W1, const float* __restrict__ b1,
    const float* __restrict__ W2, const float* __restrict__ b2,
    float* __restrict__ out) {
    __shared__ __align__(16) unsigned short Xs[2][16][256];   // 16 KB
    __shared__ float Qpart[8][128];                           // 4 KB

    int tid = threadIdx.x;
    int l = tid & 63, w = tid >> 6;        // wave 0..7
    int sr = tid >> 5, qt = tid & 31;      // staging: row 0..15, 8-float chunk
    size_t base = (size_t)blockIdx.x * 128 * 256;
    const float* xst = x + base + (size_t)sr * 256 + qt * 8;

    // ---- U fragments (u-blocks 2w, 2w+1), loaded once ----
    const unsigned short* up = Bp + (size_t)(2 * w) * 4096 + l * 8;
    bf16x8 uf0[8], uf1[8];
#pragma unroll
    for (int t = 0; t < 8; ++t) {
        uf0[t] = *(const bf16x8*)(up + t * 512);
        uf1[t] = *(const bf16x8*)(up + 4096 + t * 512);
    }

    // ---- prologue: tiles 0,1 prefetched; tile 0 converted to LDS ----
    float4 pf[2][2];
    pf[0][0] = *(const float4*)(xst);
    pf[0][1] = *(const float4*)(xst + 4);
    pf[1][0] = *(const float4*)(xst + 4096);
    pf[1][1] = *(const float4*)(xst + 4100);
    cvt_store(pf[0][0], pf[0][1], Xs[0], sr, qt);
    wg_barrier();

    int row = l & 15, kg = l >> 4;

    // ---- 8-tile pipeline: prefetch(t+2) -> compute(t) -> cvt_store(t+1) ----
#pragma unroll
    for (int t = 0; t < 8; ++t) {
        if (t + 2 < 8) {
            pf[t & 1][0] = *(const float4*)(xst + (size_t)(t + 2) * 4096);
            pf[t & 1][1] = *(const float4*)(xst + (size_t)(t + 2) * 4096 + 4);
        }
        {   // compute tile t: 8 ksteps x 2 builtin MFMAs
            const unsigned short* rp = &Xs[t & 1][row][0];
            f32x4 a0 = {0.f, 0.f, 0.f, 0.f}, a1 = {0.f, 0.f, 0.f, 0.f};
#pragma unroll
            for (int ks = 0; ks < 8; ++ks) {
                bf16x8 xf = *(const bf16x8*)(rp + (((ks << 2) | kg) ^ (row & 7)) * 8);
                a0 = __builtin_amdgcn_mfma_f32_16x16x32_bf16(uf0[ks], xf, a0, 0, 0, 0);
                a1 = __builtin_amdgcn_mfma_f32_16x16x32_bf16(uf1[ks], xf, a1, 0, 0, 0);
            }
            float q = 0.f;
#pragma unroll
            for (int j = 0; j < 4; ++j)
                q = fmaf(a0[j], a0[j], fmaf(a1[j], a1[j], q));
            q += __shfl_xor(q, 16);        // reduce the 4 n-row groups
            q += __shfl_xor(q, 32);
            if (l < 16) Qpart[w][t * 16 + l] = q;
        }
        if (t + 1 < 8)
            cvt_store(pf[(t + 1) & 1][0], pf[(t + 1) & 1][1],
                      Xs[(t + 1) & 1], sr, qt);
        wg_barrier();
    }

    // ---- epilogue: z = (P+ - P-)/(P+ + P-), MLP, sigmoid ----
    if (tid < 128) {
        float pp = Qpart[0][tid] + Qpart[1][tid] + Qpart[2][tid] + Qpart[3][tid];
        float pm = Qpart[4][tid] + Qpart[5][tid] + Qpart[6][tid] + Qpart[7][tid];
        float z = (pp - pm) / (pp + pm);
        float o = b2[0];
#pragma unroll
        for (int jj = 0; jj < 16; ++jj) {
            float h = fmaf(z, W1[jj], b1[jj]);
            h = h > 0.f ? h : 0.f;
            o = fmaf(W2[jj], h, o);
        }
        out[(size_t)blockIdx.x * 128 + tid] = 1.f / (1.f + expf(-o));
    }
}

extern "C" void kernel_launch(void* const* d_in, const int* in_sizes, int n_in,
                              void* d_out, int out_size, void* d_ws, size_t ws_size,
                              hipStream_t stream) {
    const float* x   = (const float*)d_in[0];
    const float* wts = (const float*)d_in[1];
    const float* W1  = (const float*)d_in[2];
    const float* b1  = (const float*)d_in[3];
    const float* W2  = (const float*)d_in[4];
    const float* b2  = (const float*)d_in[5];
    float* out = (float*)d_out;
    unsigned short* Bp = (unsigned short*)d_ws;   // 65536 bf16 = 128 KB

    int B = in_sizes[0] >> 8;        // 65536 samples
    qnn_setup<<<64, 256, 0, stream>>>(wts, Bp);
    qnn_main<<<B / 128, 512, 0, stream>>>(x, Bp, W1, b1, W2, b2, out);
}